// Round 2
// baseline (122.150 us; speedup 1.0000x reference)
//
#include <hip/hip_runtime.h>

// Problem constants (fixed by reference setup_inputs)
constexpr int B  = 32;
constexpr int S  = 32;
constexpr int W  = 30;
constexpr int E  = 300;
constexpr int EV = E / 4;            // 75 float4 per embedding row (1200 B, 16B-aligned)
constexpr int NSENT = B * S;         // 1024 sentences
constexpr int NTOK  = NSENT * W;     // 30720 tokens
constexpr int PARTS = 9;             // blocks per sentence; 9*250 = 2250 = W*EV float4s
constexpr int F4_PER_PART = (W * EV) / PARTS;  // 250

// Native clang vector type — accepted by __builtin_nontemporal_store
// (HIP's float4 is a class and is rejected by the builtin).
typedef float v4f __attribute__((ext_vector_type(4)));

// Output layout in d_out (flat f32, reference return order):
constexpr long OFF_EMB   = 0;                                  // [1024,30,300]
constexpr long OFF_SHARE = (long)NTOK * E;                     // 9,216,000  [32,960,300]
constexpr long OFF_MASK  = OFF_SHARE + (long)NTOK * E;         // 18,432,000 [32,960]
constexpr long OFF_WM    = OFF_MASK + (long)NTOK;              // 18,462,720 [1024,30]
constexpr long OFF_SM    = OFF_WM + (long)NTOK;                // 18,493,440 [32,32]

// ---------------------------------------------------------------------------
// Fully fused: grid = 9216 blocks (9 per sentence). Wave 0 computes the
// first-zero position via ballot+ctz; part-0 blocks write the three mask
// outputs; all blocks then gather 250 float4s of both embedding outputs.
//
// All output stores are non-temporal (outputs are write-once/never-read;
// `nt` keeps them from evicting W_emb lines from L2 between gathers).
// Gather loads stay cached. Big-stream indices kept in 32-bit.
// ---------------------------------------------------------------------------
__global__ __launch_bounds__(256) void fused_kernel(
    const int* __restrict__ input,      // [30720] token ids
    const float* __restrict__ Wemb,     // [50000*300]
    float* __restrict__ out)
{
    const int bid  = blockIdx.x;
    const int sent = bid / PARTS;
    const int part = bid - sent * PARTS;
    const int tid  = threadIdx.x;

    __shared__ int idx_s[W];
    __shared__ int tix_s[W];

    if (tid < 64) {
        const int k = tid;
        const int v = (k < W) ? input[sent * W + k] : 1;   // lanes >=30 -> nonzero
        const unsigned long long bz = __ballot(v == 0);    // bits >=30 are 0
        const int z = bz ? (int)__builtin_ctzll(bz) : W;   // first-zero position
        if (k < W) {
            idx_s[k] = v;
            tix_s[k] = (k < z) ? v : 0;                    // cumprod-keep
            if (part == 0) {
                __builtin_nontemporal_store((v != 0) ? 1.0f : 0.0f,
                                            out + OFF_WM + sent * W + k);
                __builtin_nontemporal_store((k < z) ? 1.0f : 0.0f,
                                            out + OFF_MASK + sent * W + k);
            }
        }
        if (part == 0 && k == 0) {
            constexpr unsigned long long ALLZ = (1ull << W) - 1;
            __builtin_nontemporal_store((bz != ALLZ) ? 1.0f : 0.0f,
                                        out + OFF_SM + sent);   // any nonzero
        }
    }
    __syncthreads();

    if (tid >= F4_PER_PART) return;

    const int i = part * F4_PER_PART + tid;   // 0..2249 within sentence
    const int k = i / EV;                     // word (const-div -> magic mul)
    const int q = i - k * EV;                 // float4 within row

    const int idx = idx_s[k];
    const int tix = tix_s[k];

    const v4f* __restrict__ W4 = (const v4f*)Wemb;
    const int g = sent * (W * EV) + i;        // max 2,303,999 — fits 32-bit

    v4f a = W4[idx * EV + q];                 // idx*75+q <= 3.75M — fits 32-bit
    v4f b = (tix == idx) ? a : W4[q];         // tix != idx  =>  tix == 0

    __builtin_nontemporal_store(a, ((v4f*)(out + OFF_EMB))   + g);
    __builtin_nontemporal_store(b, ((v4f*)(out + OFF_SHARE)) + g);
}

extern "C" void kernel_launch(void* const* d_in, const int* in_sizes, int n_in,
                              void* d_out, int out_size, void* d_ws, size_t ws_size,
                              hipStream_t stream) {
    const int*   input = (const int*)d_in[0];     // [32,32,30] token ids
    const float* Wemb  = (const float*)d_in[1];   // [50000,300]
    float*       out   = (float*)d_out;

    fused_kernel<<<NSENT * PARTS, 256, 0, stream>>>(input, Wemb, out);
}